// Round 3
// baseline (636.536 us; speedup 1.0000x reference)
//
#include <hip/hip_runtime.h>
#include <hip/hip_fp16.h>

// Problem: T=8192, D=2048, R=2048
//   a = sigmoid(x@W_a); b = (x@W_b)*(1-a)
//   h_t = a_t*h_{t-1} + b_t  (h_{-1} = h0)
//   y = tanh(h)@W_out + x@W_skip
// Outputs: next_h [T,R] fp32, y [T,D] fp32 (concat in d_out)

#define T_DIM 8192
#define D_DIM 2048
#define R_DIM 2048
#define NCH   128          // scan chunks
#define LCH   64           // T_DIM / NCH

typedef _Float16 f16;
typedef _Float16 f16x2 __attribute__((ext_vector_type(2)));
typedef _Float16 f16x4 __attribute__((ext_vector_type(4)));
typedef _Float16 f16x8 __attribute__((ext_vector_type(8)));
typedef float    f32x16 __attribute__((ext_vector_type(16)));

#define AS1 __attribute__((address_space(1)))
#define AS3 __attribute__((address_space(3)))
#define GLOAD_LDS16(g, l) \
  __builtin_amdgcn_global_load_lds((const AS1 void*)(g), (AS3 void*)(l), 16, 0, 0)

// LDS XOR swizzle: XOR bits 4-6 with bits 7-9 (involution; bits 7-9 untouched).
__device__ __forceinline__ int swz(int p) { return p ^ (((p >> 7) & 7) << 4); }

__device__ __forceinline__ float sigmoid_f(float z) {
  return __builtin_amdgcn_rcpf(1.0f + __expf(-z));
}
__device__ __forceinline__ float tanh_f(float x) {
  // 1 - 2/(exp(2x)+1); exp overflow -> inf -> rcp -> 0 -> +1; underflow -> -1.
  return 1.0f - 2.0f * __builtin_amdgcn_rcpf(1.0f + __expf(2.0f * x));
}

// ---------------- conversion kernels ----------------

__global__ __launch_bounds__(256) void cvt_f32_f16_kernel(
    const float* __restrict__ in, f16* __restrict__ out, int n4) {
  int i = blockIdx.x * 256 + threadIdx.x;
  if (i >= n4) return;
  float4 v = ((const float4*)in)[i];
  f16x4 o; o.x = (f16)v.x; o.y = (f16)v.y; o.z = (f16)v.z; o.w = (f16)v.w;
  ((f16x4*)out)[i] = o;
}

// 4 matrices [2048][2048] f32 -> f16 transposed, selected by blockIdx.z
__global__ __launch_bounds__(256) void transpose_cvt_kernel(
    const float* __restrict__ s0, f16* __restrict__ d0,
    const float* __restrict__ s1, f16* __restrict__ d1,
    const float* __restrict__ s2, f16* __restrict__ d2,
    const float* __restrict__ s3, f16* __restrict__ d3) {
  const float* in; f16* out;
  int z = blockIdx.z;
  if (z == 0)      { in = s0; out = d0; }
  else if (z == 1) { in = s1; out = d1; }
  else if (z == 2) { in = s2; out = d2; }
  else             { in = s3; out = d3; }
  __shared__ float tile[32][33];
  int bx = blockIdx.x * 32, by = blockIdx.y * 32;
  int tx = threadIdx.x, ty = threadIdx.y;      // block (32,8)
  #pragma unroll
  for (int i = 0; i < 32; i += 8)
    tile[ty + i][tx] = in[(size_t)(by + ty + i) * 2048 + bx + tx];
  __syncthreads();
  #pragma unroll
  for (int i = 0; i < 32; i += 8)
    out[(size_t)(bx + ty + i) * 2048 + by + tx] = (f16)tile[tx][ty + i];
}

// ---------------- GEMM: 256x128 tile, BK=32, 8 waves, 3-buffer pipeline --------
// C[8192 x 2048] = A1 @ B1^T (+ A2 @ B2^T); A [M][2048] f16, B [N][2048] f16.
// 32x32x16_f16 MFMA; wave grid 4M x 2N, per-wave C = 64x64 (2x2 frags of 32x32).
// 3 LDS buffers x 24 KB = 72 KB -> 2 blocks/CU (16 waves/CU) for cross-block
// overlap of the barrier/vmcnt window. Counted vmcnt(3) steady state.
// MODE 0: store fp32. MODE 1: store f16 (raw z).
template <int MODE>
__global__ __launch_bounds__(512, 4) void gemm_kernel(
    const f16* __restrict__ A1, const f16* __restrict__ B1, int NT1,
    const f16* __restrict__ A2, const f16* __restrict__ B2, int NT2,
    void* __restrict__ outp) {
  __shared__ __align__(16) char lds[3 * 24576];   // per buf: A 16KB + B 8KB
  const int tid = threadIdx.x;
  const int l = tid & 63, w = tid >> 6;           // 8 waves
  const int wrow = w >> 1, wcol = w & 1;          // 4M x 2N
  const int l31 = l & 31, hi = l >> 5;

  // XCD swizzle: 512 blocks; XCD k gets m-panels 4k..4k+3 x all 16 n-panels
  const int id = blockIdx.x;
  const int sw = (id & 7) * 64 + (id >> 3);
  const int m0 = (sw >> 4) * 256, n0 = (sw & 15) * 128;
  const int NTtot = NT1 + NT2;

  // staging: per-thread global source offsets (pre-swizzled). Row stride 4096 B.
  int gA0, gA1, gB0;
  {
    int p0 = tid * 16;               // A chunk q=0 (16KB buf)
    int p1 = (512 + tid) * 16;       // A chunk q=1
    int pb = tid * 16;               // B chunk (8KB buf)
    int lg;
    lg = swz(p0); gA0 = (lg >> 6) * 4096 + (lg & 63);
    lg = swz(p1); gA1 = (lg >> 6) * 4096 + (lg & 63);
    lg = swz(pb); gB0 = (lg >> 6) * 4096 + (lg & 63);
  }
  // swizzled LDS read offsets: A row = wrow*64+m*32+l31, B row = wcol*64+n*32+l31
  int oA[2][2], oB[2][2];
  #pragma unroll
  for (int m = 0; m < 2; m++)
    #pragma unroll
    for (int kk = 0; kk < 2; kk++)
      oA[m][kk] = swz((wrow * 64 + m * 32 + l31) * 64 + kk * 32 + hi * 16);
  #pragma unroll
  for (int n = 0; n < 2; n++)
    #pragma unroll
    for (int kk = 0; kk < 2; kk++)
      oB[n][kk] = swz((wcol * 64 + n * 32 + l31) * 64 + kk * 32 + hi * 16);

  f32x16 acc[2][2];
  #pragma unroll
  for (int m = 0; m < 2; m++)
    #pragma unroll
    for (int n = 0; n < 2; n++)
      #pragma unroll
      for (int r = 0; r < 16; r++)
        acc[m][n][r] = 0.f;

  auto stage = [&](int tf, int slot) {
    const f16* At; const f16* Bt; int kt;
    if (tf < NT1) { At = A1; Bt = B1; kt = tf; }
    else          { At = A2; Bt = B2; kt = tf - NT1; }
    const char* gA = (const char*)At + (size_t)m0 * 4096 + kt * 64;
    const char* gB = (const char*)Bt + (size_t)n0 * 4096 + kt * 64;
    char* dA = lds + slot * 24576;
    char* dB = dA + 16384;
    GLOAD_LDS16(gA + gA0, dA + (w * 64) * 16);
    GLOAD_LDS16(gA + gA1, dA + (512 + w * 64) * 16);
    GLOAD_LDS16(gB + gB0, dB + (w * 64) * 16);
  };

  stage(0, 0); stage(1, 1);
  int cs = 0;                                     // slot of tile t
  for (int t = 0; t < NTtot; ++t) {
    if (t < NTtot - 1) asm volatile("s_waitcnt vmcnt(3)" ::: "memory");
    else               asm volatile("s_waitcnt vmcnt(0)" ::: "memory");
    asm volatile("s_barrier" ::: "memory");
    if (t + 2 < NTtot) {
      int ss = cs + 2; if (ss >= 3) ss -= 3;
      stage(t + 2, ss);
    }
    const char* bA = lds + cs * 24576;
    const char* bB = bA + 16384;
    __builtin_amdgcn_s_setprio(1);
    #pragma unroll
    for (int kk = 0; kk < 2; kk++) {
      f16x8 a0 = *(const f16x8*)(bA + oA[0][kk]);
      f16x8 a1 = *(const f16x8*)(bA + oA[1][kk]);
      f16x8 b0 = *(const f16x8*)(bB + oB[0][kk]);
      f16x8 b1 = *(const f16x8*)(bB + oB[1][kk]);
      acc[0][0] = __builtin_amdgcn_mfma_f32_32x32x16_f16(a0, b0, acc[0][0], 0, 0, 0);
      acc[0][1] = __builtin_amdgcn_mfma_f32_32x32x16_f16(a0, b1, acc[0][1], 0, 0, 0);
      acc[1][0] = __builtin_amdgcn_mfma_f32_32x32x16_f16(a1, b0, acc[1][0], 0, 0, 0);
      acc[1][1] = __builtin_amdgcn_mfma_f32_32x32x16_f16(a1, b1, acc[1][1], 0, 0, 0);
    }
    __builtin_amdgcn_s_setprio(0);
    cs = (cs == 2) ? 0 : cs + 1;
  }

  // epilogue; 32x32 C/D layout: col = lane&31, row = (reg&3)+8*(reg>>2)+4*(lane>>5)
  const int r0 = m0 + wrow * 64 + 4 * hi;
  const int c0 = n0 + wcol * 64 + l31;
  #pragma unroll
  for (int m = 0; m < 2; m++)
    #pragma unroll
    for (int n = 0; n < 2; n++)
      #pragma unroll
      for (int r = 0; r < 16; r++) {
        int row = r0 + m * 32 + (r & 3) + 8 * (r >> 2);
        size_t idx = (size_t)row * 2048 + (c0 + n * 32);
        float v = acc[m][n][r];
        if (MODE == 0) ((float*)outp)[idx] = v;
        else           ((f16*)outp)[idx]   = (f16)v;
      }
}

// ---------------- chunked scan with fused gating ----------------
// za, zb are raw pre-activation f16; a = sigmoid(za), b = zb*(1-a).

__global__ __launch_bounds__(256) void scan_pass_a(
    const f16* __restrict__ za, const f16* __restrict__ zb,
    float* __restrict__ Ac, float* __restrict__ Bc) {
  int tid = blockIdx.x * 256 + threadIdx.x;   // NCH * R/2 threads
  int c  = tid >> 10;
  int r2 = (tid & 1023) << 1;
  const f16* pa = za + (size_t)c * LCH * R_DIM + r2;
  const f16* pb = zb + (size_t)c * LCH * R_DIM + r2;
  float A0 = 1.f, B0 = 0.f, A1 = 1.f, B1 = 0.f;
  #pragma unroll 8
  for (int i = 0; i < LCH; i++) {
    f16x2 av = *(const f16x2*)(pa + (size_t)i * R_DIM);
    f16x2 bv = *(const f16x2*)(pb + (size_t)i * R_DIM);
    float a0 = sigmoid_f((float)av.x), a1 = sigmoid_f((float)av.y);
    float b0 = (float)bv.x * (1.0f - a0), b1 = (float)bv.y * (1.0f - a1);
    B0 = fmaf(a0, B0, b0); A0 *= a0;
    B1 = fmaf(a1, B1, b1); A1 *= a1;
  }
  size_t o = (size_t)c * R_DIM + r2;
  *(float2*)&Ac[o] = make_float2(A0, A1);
  *(float2*)&Bc[o] = make_float2(B0, B1);
}

__global__ __launch_bounds__(256) void scan_carry(
    const float* __restrict__ Ac, const float* __restrict__ Bc,
    const float* __restrict__ h0, float* __restrict__ carry) {
  int r = blockIdx.x * 256 + threadIdx.x;     // R threads
  float h = h0[r];
  #pragma unroll 8
  for (int c = 0; c < NCH; c++) {
    size_t o = (size_t)c * R_DIM + r;
    carry[o] = h;
    h = fmaf(Ac[o], h, Bc[o]);
  }
}

__global__ __launch_bounds__(256) void scan_pass_c(
    const f16* __restrict__ za, const f16* __restrict__ zb,
    const float* __restrict__ carry,
    float* __restrict__ hout, f16* __restrict__ th) {
  int tid = blockIdx.x * 256 + threadIdx.x;
  int c  = tid >> 10;
  int r2 = (tid & 1023) << 1;
  size_t base = (size_t)c * LCH * R_DIM + r2;
  const f16* pa = za + base;
  const f16* pb = zb + base;
  float2 hv = *(const float2*)&carry[(size_t)c * R_DIM + r2];
  float hA = hv.x, hB = hv.y;
  #pragma unroll 4
  for (int i = 0; i < LCH; i++) {
    f16x2 av = *(const f16x2*)(pa + (size_t)i * R_DIM);
    f16x2 bv = *(const f16x2*)(pb + (size_t)i * R_DIM);
    float a0 = sigmoid_f((float)av.x), a1 = sigmoid_f((float)av.y);
    hA = fmaf(a0, hA, (float)bv.x * (1.0f - a0));
    hB = fmaf(a1, hB, (float)bv.y * (1.0f - a1));
    size_t o = base + (size_t)i * R_DIM;
    *(float2*)&hout[o] = make_float2(hA, hB);
    f16x2 tv; tv.x = (f16)tanh_f(hA); tv.y = (f16)tanh_f(hB);
    *(f16x2*)(th + o) = tv;
  }
}

// ---------------- launch ----------------

extern "C" void kernel_launch(void* const* d_in, const int* in_sizes, int n_in,
                              void* d_out, int out_size, void* d_ws, size_t ws_size,
                              hipStream_t stream) {
  const float* x      = (const float*)d_in[0];
  const float* h0     = (const float*)d_in[1];
  const float* W_a    = (const float*)d_in[2];
  const float* W_b    = (const float*)d_in[3];
  const float* W_out  = (const float*)d_in[4];
  const float* W_skip = (const float*)d_in[5];
  float* out_h = (float*)d_out;                       // [T,R]
  float* out_y = out_h + (size_t)T_DIM * R_DIM;       // [T,D]

  char* ws = (char*)d_ws;
  size_t off = 0;
  auto alloc = [&](size_t bytes) -> void* {
    void* p = ws + off;
    off += (bytes + 255) & ~(size_t)255;
    return p;
  };
  f16*  x16   = (f16*)alloc((size_t)T_DIM * D_DIM * 2);
  f16*  WaT   = (f16*)alloc((size_t)D_DIM * R_DIM * 2);
  f16*  WbT   = (f16*)alloc((size_t)D_DIM * R_DIM * 2);
  f16*  WoutT = (f16*)alloc((size_t)R_DIM * D_DIM * 2);
  f16*  WskT  = (f16*)alloc((size_t)D_DIM * D_DIM * 2);
  f16*  za16  = (f16*)alloc((size_t)T_DIM * R_DIM * 2);
  f16*  zb16  = (f16*)alloc((size_t)T_DIM * R_DIM * 2);
  f16*  th16  = (f16*)alloc((size_t)T_DIM * R_DIM * 2);
  float* Ac   = (float*)alloc((size_t)NCH * R_DIM * 4);
  float* Bc   = (float*)alloc((size_t)NCH * R_DIM * 4);
  float* carry= (float*)alloc((size_t)NCH * R_DIM * 4);

  // 1) fp32 -> fp16 conversions and transposed weights (one launch for all 4)
  {
    int n4 = T_DIM * D_DIM / 4;
    cvt_f32_f16_kernel<<<(n4 + 255) / 256, 256, 0, stream>>>(x, x16, n4);
  }
  {
    dim3 tg(64, 64, 4), tb(32, 8);
    transpose_cvt_kernel<<<tg, tb, 0, stream>>>(W_a, WaT, W_b, WbT,
                                                W_out, WoutT, W_skip, WskT);
  }

  // 2) za = x@W_a, zb = x@W_b (raw f16; gating fused into scan)
  const int NT = D_DIM / 32;  // 64 K-tiles
  gemm_kernel<1><<<512, 512, 0, stream>>>(x16, WaT, NT, nullptr, nullptr, 0, za16);
  gemm_kernel<1><<<512, 512, 0, stream>>>(x16, WbT, NT, nullptr, nullptr, 0, zb16);

  // 3) chunked scan -> next_h (fp32, d_out) and tanh(h) (f16)
  scan_pass_a<<<NCH * (R_DIM / 2) / 256, 256, 0, stream>>>(za16, zb16, Ac, Bc);
  scan_carry <<<R_DIM / 256, 256, 0, stream>>>(Ac, Bc, h0, carry);
  scan_pass_c<<<NCH * (R_DIM / 2) / 256, 256, 0, stream>>>(za16, zb16, carry, out_h, th16);

  // 4) y = tanh(h)@W_out + x@W_skip  (K-concatenated dual-panel GEMM)
  gemm_kernel<0><<<512, 512, 0, stream>>>(th16, WoutT, NT, x16, WskT, NT, out_y);
}